// Round 3
// baseline (91.657 us; speedup 1.0000x reference)
//
#include <hip/hip_runtime.h>

#define TPB 256
#define RPB 4                         // rows per tile (4-row tiles)
#define SEQ_L 2048
#define NCH 8                         // 256-wide j-chunks
#define NBATCH 8
#define NT4 512                       // 4-row tiles per batch
#define NPAIR 256                     // tile pairs (t, 511-t), t in 0..255
#define NBLOCKS (NBATCH * NPAIR)      // 2048  == 256 CU x 8 blocks/CU
#define NWAVE (TPB / 64)

static constexpr float kBondTol  = 0.4f;
static constexpr float kClashTol = 1.5f;
static constexpr float kIdeal    = 3.8f;
static constexpr float kEps      = 1e-8f;
static constexpr float kThresh2  = 2.25f;   // 1.5^2: d2 >= this -> relu == 0
static constexpr float kFarBase  = 1.0e5f;  // masked-point sentinel base
static constexpr float kHugeD2   = 1.0e12f; // "not a pair" d2 sentinel

__device__ __forceinline__ float wred(float v) {
#pragma unroll
  for (int o = 32; o > 0; o >>= 1) v += __shfl_down(v, o, 64);
  return v;
}

// LDS-free design: per-batch data (32 KB) is fully L2-resident, so lanes read
// j-points directly from global (L2 ~200cy, prefetch-hidden) and rows via
// wave-uniform loads. No staging loop, no barriers in the hot path, ~0 LDS ->
// occupancy is VGPR-capped only: __launch_bounds__(256,8) targets 8 blocks/CU
// (32 waves/CU, 2x every previous version). Grid = 2048 paired 4-row tiles
// {t, 511-t}: k0A+k0B == 7, so every block does exactly 9 uniform 4-row
// tile-computes — one exact dispatch round at 8/CU.
// Masks are geometric sentinels (masked points relocated to spaced far-away
// positions, spacing 4 > 1.5): the hot loop has NO mask weighting.
// pm uses the exact algebra  pm_batch = msum^2 - sum_i mi*nm_i ; msum^2 is
// contributed by one designated block per batch (t == 0).
// Fused finish (cheap, unlike round-1's wbl2 disaster): device-scope atomic
// stores publish the partial (write-through to coherence point, no L2 flush),
// s_waitcnt vmcnt(0), ticket atomicAdd; last block's wave 0 reduces all 2048
// partials in fixed (deterministic) order and writes out[].
__global__ __launch_bounds__(TPB, 8) void viol_fused(
    const float* __restrict__ pos,    // [B, L, 3]
    const float* __restrict__ mask,   // [B, L]
    float4* __restrict__ partial,     // [NBLOCKS] in d_ws (atomics only)
    unsigned* __restrict__ counter,   // 4B in d_ws, memset to 0 each launch
    float* __restrict__ out) {        // [3]
  __shared__ float red4[NWAVE][4];
  __shared__ float redm[NWAVE];

  const int b   = blockIdx.x & 7;     // batch -> XCD-pinned L2 reuse
  const int t   = blockIdx.x >> 3;    // pair index 0..255
  const int i0A = t << 2;             // low 4-row tile
  const int i0B = (NT4 - 1 - t) << 2; // high 4-row tile
  const int k0A = t >> 6;             // 0..3
  const int k0B = (NT4 - 1 - t) >> 6; // 4..7  (k0A + k0B == 7)
  const int tid  = (int)threadIdx.x;
  const int wid  = tid >> 6;
  const int lane = tid & 63;

  const float* pb = pos  + (size_t)b * SEQ_L * 3;
  const float* mb = mask + (size_t)b * SEQ_L;

  // ---- designated blocks (t==0): batch mask sum for the msum^2 term ----
  float msq = 0.f;
  if (t == 0) {
    float mp = 0.f;
#pragma unroll
    for (int it = 0; it < NCH; ++it) mp += mb[tid + (it << 8)];
    mp = wred(mp);
    if (lane == 0) redm[wid] = mp;
    __syncthreads();                  // block-uniform branch: legal
    const float ms = redm[0] + redm[1] + redm[2] + redm[3];
    msq = ms * ms;
  }

  // ---- rows (sentineled), wave-uniform loads -> scalar regs ----
  float pxA[RPB], pyA[RPB], pzA[RPB], accA[RPB];
  float pxB[RPB], pyB[RPB], pzB[RPB], accB[RPB];
#pragma unroll
  for (int q = 0; q < RPB; ++q) {
    const int iA = i0A + q, iB = i0B + q;
    float xA = pb[3 * iA], yA = pb[3 * iA + 1], zA = pb[3 * iA + 2];
    float xB = pb[3 * iB], yB = pb[3 * iB + 1], zB = pb[3 * iB + 2];
    if (mb[iA] == 0.f) { xA = kFarBase + 4.f * (float)iA; yA = 0.f; zA = 0.f; }
    if (mb[iB] == 0.f) { xB = kFarBase + 4.f * (float)iB; yB = 0.f; zB = 0.f; }
    pxA[q] = xA; pyA[q] = yA; pzA[q] = zA;
    pxB[q] = xB; pyB[q] = yB; pzB[q] = zB;
    accA[q] = 0.f; accB[q] = 0.f;
  }

  // ---- sweep chunks k0A..7 straight from L2, next-chunk prefetch ----
  {
    int jg = tid + (k0A << 8);
    float cx = pb[3 * jg], cy = pb[3 * jg + 1], cz = pb[3 * jg + 2];
    if (mb[jg] == 0.f) { cx = kFarBase + 4.f * (float)jg; cy = 0.f; cz = 0.f; }

    for (int k = k0A; k < NCH; ++k) {
      const int kn = (k + 1 < NCH) ? k + 1 : k;     // harmless re-read at end
      const int jn = tid + (kn << 8);
      float nx = pb[3 * jn], ny = pb[3 * jn + 1], nz = pb[3 * jn + 2];
      const float nm = mb[jn];
      const int j = tid + (k << 8);

      float d2r[RPB];
      // --- tile A (active every iteration; diagonal when k == k0A) ---
#pragma unroll
      for (int q = 0; q < RPB; ++q) {
        const float dx = cx - pxA[q], dy = cy - pyA[q], dz = cz - pzA[q];
        d2r[q] = fmaf(dx, dx, fmaf(dy, dy, dz * dz));
      }
      if (k == k0A) {
#pragma unroll
        for (int q = 0; q < RPB; ++q)
          d2r[q] = (j > i0A + q) ? d2r[q] : kHugeD2;  // strict upper triangle
      }
      {
        const float mv = fminf(fminf(d2r[0], d2r[1]), fminf(d2r[2], d2r[3]));
        if (__ballot(mv < kThresh2) != 0ull) {
#pragma unroll
          for (int q = 0; q < RPB; ++q) {
            const float dist = __builtin_amdgcn_sqrtf(d2r[q] + kEps);
            accA[q] += fmaxf(kClashTol - dist, 0.f);
          }
        }
      }
      // --- tile B (active for k >= k0B; diagonal when k == k0B) ---
      if (k >= k0B) {
#pragma unroll
        for (int q = 0; q < RPB; ++q) {
          const float dx = cx - pxB[q], dy = cy - pyB[q], dz = cz - pzB[q];
          d2r[q] = fmaf(dx, dx, fmaf(dy, dy, dz * dz));
        }
        if (k == k0B) {
#pragma unroll
          for (int q = 0; q < RPB; ++q)
            d2r[q] = (j > i0B + q) ? d2r[q] : kHugeD2;
        }
        const float mv = fminf(fminf(d2r[0], d2r[1]), fminf(d2r[2], d2r[3]));
        if (__ballot(mv < kThresh2) != 0ull) {
#pragma unroll
          for (int q = 0; q < RPB; ++q) {
            const float dist = __builtin_amdgcn_sqrtf(d2r[q] + kEps);
            accB[q] += fmaxf(kClashTol - dist, 0.f);
          }
        }
      }
      // sentinel-apply prefetched point, rotate
      if (nm == 0.f) { nx = kFarBase + 4.f * (float)jn; ny = 0.f; nz = 0.f; }
      cx = nx; cy = ny; cz = nz;
    }
  }

  float cv = 0.f;
#pragma unroll
  for (int q = 0; q < RPB; ++q) cv += accA[q] + accB[q];

  // ---- tail (8 rows): near-diagonal cancel + bond + pm stencil ----
  float bv = 0.f, bm = 0.f, pm = 0.f;
  if (tid < 8) {
    const int i = (tid < 4) ? (i0A + tid) : (i0B + (tid - 4));
    const float mi = mb[i];
    const float xi = pb[3 * i], yi = pb[3 * i + 1], zi = pb[3 * i + 2];
    float sxi = xi, syi = yi, szi = zi;                 // sentineled copy
    if (mi == 0.f) { sxi = kFarBase + 4.f * (float)i; syi = 0.f; szi = 0.f; }
    const int jhi = (i + 2 > SEQ_L - 1) ? SEQ_L - 1 : i + 2;

    float nv = 0.f;                   // cancel exactly what the sweep added
    for (int jj = i + 1; jj <= jhi; ++jj) {
      float xj = pb[3 * jj], yj = pb[3 * jj + 1], zj = pb[3 * jj + 2];
      if (mb[jj] == 0.f) { xj = kFarBase + 4.f * (float)jj; yj = 0.f; zj = 0.f; }
      const float dx = xj - sxi, dy = yj - syi, dz = zj - szi;
      const float dist = __builtin_amdgcn_sqrtf(dx*dx + dy*dy + dz*dz + kEps);
      nv += fmaxf(kClashTol - dist, 0.f);
    }
    cv -= nv;

    float nm_ = 0.f;                  // real masks, |i-j|<=2 incl. j==i
    const int jlo = (i - 2 < 0) ? 0 : i - 2;
    for (int jj = jlo; jj <= jhi; ++jj) nm_ += mb[jj];
    pm = -mi * nm_;                   // msum^2 added by designated blocks

    if (i < SEQ_L - 1) {              // bond term: RAW positions, mask product
      const float dx = pb[3*(i+1)]   - xi;
      const float dy = pb[3*(i+1)+1] - yi;
      const float dz = pb[3*(i+1)+2] - zi;
      const float dist = __builtin_amdgcn_sqrtf(dx*dx + dy*dy + dz*dz + kEps);
      const float mj = mb[i + 1];
      bv = fmaxf(fabsf(dist - kIdeal) - kBondTol, 0.f) * mi * mj;
      bm = mi * mj;
    }
  }

  // ---- block reduction ----
  bv = wred(bv); bm = wred(bm); cv = wred(cv); pm = wred(pm);
  if (lane == 0) {
    red4[wid][0] = bv; red4[wid][1] = bm;
    red4[wid][2] = cv; red4[wid][3] = pm;
  }
  __syncthreads();

  int lastflag = 0;
  if (tid == 0) {
    float tbv = 0.f, tbm = 0.f, tcv = 0.f, tpm = 0.f;
#pragma unroll
    for (int w = 0; w < NWAVE; ++w) {
      tbv += red4[w][0]; tbm += red4[w][1];
      tcv += red4[w][2]; tpm += red4[w][3];
    }
    tpm += msq;                       // nonzero only in designated blocks
    // publish via device-scope atomic stores: write-through to coherence
    // point, visible to the last block's atomic loads — NO buffer_wbl2.
    float* p = (float*)(partial + blockIdx.x);
    __hip_atomic_store(p + 0, tbv,       __ATOMIC_RELAXED, __HIP_MEMORY_SCOPE_AGENT);
    __hip_atomic_store(p + 1, tbm,       __ATOMIC_RELAXED, __HIP_MEMORY_SCOPE_AGENT);
    __hip_atomic_store(p + 2, 2.f * tcv, __ATOMIC_RELAXED, __HIP_MEMORY_SCOPE_AGENT);
    __hip_atomic_store(p + 3, tpm,       __ATOMIC_RELAXED, __HIP_MEMORY_SCOPE_AGENT);
    asm volatile("s_waitcnt vmcnt(0)" ::: "memory");   // stores performed
    lastflag = ((unsigned)atomicAdd(counter, 1u) == NBLOCKS - 1u) ? 1 : 0;
  }

  // ---- last block, wave 0 only: deterministic final reduce ----
  if (wid == 0) {
    lastflag = __shfl(lastflag, 0, 64);
    if (lastflag) {
      float rbv = 0.f, rbm = 0.f, rcv = 0.f, rpm = 0.f;
      for (int idx = lane; idx < NBLOCKS; idx += 64) {   // fixed order
        const unsigned long long* q = (const unsigned long long*)(partial + idx);
        const unsigned long long lo =
            __hip_atomic_load(q + 0, __ATOMIC_RELAXED, __HIP_MEMORY_SCOPE_AGENT);
        const unsigned long long hi =
            __hip_atomic_load(q + 1, __ATOMIC_RELAXED, __HIP_MEMORY_SCOPE_AGENT);
        rbv += __uint_as_float((unsigned)(lo & 0xffffffffull));
        rbm += __uint_as_float((unsigned)(lo >> 32));
        rcv += __uint_as_float((unsigned)(hi & 0xffffffffull));
        rpm += __uint_as_float((unsigned)(hi >> 32));
      }
      rbv = wred(rbv); rbm = wred(rbm); rcv = wred(rcv); rpm = wred(rpm);
      if (lane == 0) {
        const float bond  = rbv / (rbm + kEps);
        const float clash = rcv / (rpm + kEps);
        out[0] = bond;
        out[1] = clash;
        out[2] = bond + clash;
      }
    }
  }
}

extern "C" void kernel_launch(void* const* d_in, const int* in_sizes, int n_in,
                              void* d_out, int out_size, void* d_ws, size_t ws_size,
                              hipStream_t stream) {
  const float* pos  = (const float*)d_in[0];
  const float* mask = (const float*)d_in[1];
  float* out = (float*)d_out;
  float4* partial   = (float4*)d_ws;                     // 2048 * 16 B = 32 KB
  unsigned* counter = (unsigned*)((char*)d_ws + NBLOCKS * sizeof(float4));

  // ticket must be 0 each replay (workspace is poisoned between iterations);
  // 4-byte memset node ahead of the kernel — graph-capture safe (round 1).
  hipMemsetAsync(counter, 0, sizeof(unsigned), stream);
  viol_fused<<<dim3(NBLOCKS), dim3(TPB), 0, stream>>>(pos, mask, partial,
                                                      counter, out);
}

// Round 4
// 65.166 us; speedup vs baseline: 1.4065x; 1.4065x over previous
//
#include <hip/hip_runtime.h>

#define TPB 256
#define RPB 4                         // rows per tile (4-row tiles)
#define SEQ_L 2048
#define NCH 8                         // 256-wide j-chunks
#define NBATCH 8
#define NT4 512                       // 4-row tiles per batch
#define NPAIR 256                     // tile pairs (t, 511-t), t in 0..255
#define NBLOCKS (NBATCH * NPAIR)      // 2048  == 256 CU x 8 blocks/CU
#define NWAVE (TPB / 64)

static constexpr float kBondTol  = 0.4f;
static constexpr float kClashTol = 1.5f;
static constexpr float kIdeal    = 3.8f;
static constexpr float kEps      = 1e-8f;
static constexpr float kThresh2  = 2.25f;   // 1.5^2: d2 >= this -> relu == 0
static constexpr float kFarBase  = 1.0e5f;  // masked-point sentinel base
static constexpr float kHugeD2   = 1.0e12f; // "not a pair" d2 sentinel

__device__ __forceinline__ float wred(float v) {
#pragma unroll
  for (int o = 32; o > 0; o >>= 1) v += __shfl_down(v, o, 64);
  return v;
}

// Round-3 compute (proven correct, absmax 0) + round-0 finish (proven fast).
// r1/r3 showed the 2048 same-address ticket atomicAdds serialize at ~20ns
// each (~41us = the whole kernel time, both rounds, regardless of compute
// structure). So: NO atomics, NO fences — one plain float4 store per block,
// tiny second kernel reduces 2048 partials deterministically.
// Compute: LDS-free. Per-batch data (32 KB) is L2-resident (FETCH_SIZE
// confirmed ~0 HBM); lanes read j-points straight from L2 with DEPTH-2
// software prefetch; rows via wave-uniform loads. No hot-path barriers,
// LDS ~= 0, VGPR ~40 -> 8 blocks/CU (32 waves/CU). Grid = 2048 paired
// 4-row tiles {t, 511-t}: k0A+k0B == 7 -> exactly 9 uniform 4-row
// chunk-computes per block, one exact dispatch round at 8/CU.
// Masks are geometric sentinels (masked points relocated to spaced far-away
// positions, spacing 4 > 1.5): hot loop has NO mask weighting. Pair-mask
// denominator is analytic: pm_batch = msum^2 - sum_i mi*nm_i; msum^2 is
// contributed by the designated t==0 block of each batch.
__global__ __launch_bounds__(TPB, 8) void viol_main(
    const float* __restrict__ pos,    // [B, L, 3]
    const float* __restrict__ mask,   // [B, L]
    float4* __restrict__ partial) {   // [NBLOCKS]: (bv, bm, 2*cv_half, pm)
  __shared__ float red4[NWAVE][4];
  __shared__ float redm[NWAVE];

  const int b   = blockIdx.x & 7;     // batch -> XCD-pinned L2 reuse
  const int t   = blockIdx.x >> 3;    // pair index 0..255
  const int i0A = t << 2;             // low 4-row tile
  const int i0B = (NT4 - 1 - t) << 2; // high 4-row tile
  const int k0A = t >> 6;             // 0..3
  const int k0B = (NT4 - 1 - t) >> 6; // 4..7  (k0A + k0B == 7)
  const int tid  = (int)threadIdx.x;
  const int wid  = tid >> 6;
  const int lane = tid & 63;

  const float* pb = pos  + (size_t)b * SEQ_L * 3;
  const float* mb = mask + (size_t)b * SEQ_L;

  // ---- designated blocks (t==0): batch mask sum for the msum^2 term ----
  float msq = 0.f;
  if (t == 0) {
    float mp = 0.f;
#pragma unroll
    for (int it = 0; it < NCH; ++it) mp += mb[tid + (it << 8)];
    mp = wred(mp);
    if (lane == 0) redm[wid] = mp;
    __syncthreads();                  // block-uniform branch: legal
    const float ms = redm[0] + redm[1] + redm[2] + redm[3];
    msq = ms * ms;
  }

  // ---- rows (sentineled), wave-uniform loads -> regs ----
  float pxA[RPB], pyA[RPB], pzA[RPB], accA[RPB];
  float pxB[RPB], pyB[RPB], pzB[RPB], accB[RPB];
#pragma unroll
  for (int q = 0; q < RPB; ++q) {
    const int iA = i0A + q, iB = i0B + q;
    float xA = pb[3 * iA], yA = pb[3 * iA + 1], zA = pb[3 * iA + 2];
    float xB = pb[3 * iB], yB = pb[3 * iB + 1], zB = pb[3 * iB + 2];
    if (mb[iA] == 0.f) { xA = kFarBase + 4.f * (float)iA; yA = 0.f; zA = 0.f; }
    if (mb[iB] == 0.f) { xB = kFarBase + 4.f * (float)iB; yB = 0.f; zB = 0.f; }
    pxA[q] = xA; pyA[q] = yA; pzA[q] = zA;
    pxB[q] = xB; pyB[q] = yB; pzB[q] = zB;
    accA[q] = 0.f; accB[q] = 0.f;
  }

  // ---- sweep chunks k0A..7 from L2 with DEPTH-2 rolling prefetch ----
  {
    const int jg0 = tid + (k0A << 8);
    const int jg1 = tid + ((k0A + 1) << 8);       // k0A+1 <= 4 < 8 always
    float c0x = pb[3 * jg0], c0y = pb[3 * jg0 + 1], c0z = pb[3 * jg0 + 2];
    const float m0 = mb[jg0];
    float c1x = pb[3 * jg1], c1y = pb[3 * jg1 + 1], c1z = pb[3 * jg1 + 2];
    const float m1 = mb[jg1];
    if (m0 == 0.f) { c0x = kFarBase + 4.f * (float)jg0; c0y = 0.f; c0z = 0.f; }
    if (m1 == 0.f) { c1x = kFarBase + 4.f * (float)jg1; c1y = 0.f; c1z = 0.f; }

    for (int k = k0A; k < NCH; ++k) {
      const int kn = (k + 2 < NCH) ? k + 2 : NCH - 1;   // dup re-read at end
      const int jn = tid + (kn << 8);
      float nx = pb[3 * jn], ny = pb[3 * jn + 1], nz = pb[3 * jn + 2];
      const float nmm = mb[jn];
      const int j = tid + (k << 8);

      float d2r[RPB];
      // --- tile A (active every iteration; diagonal when k == k0A) ---
#pragma unroll
      for (int q = 0; q < RPB; ++q) {
        const float dx = c0x - pxA[q], dy = c0y - pyA[q], dz = c0z - pzA[q];
        d2r[q] = fmaf(dx, dx, fmaf(dy, dy, dz * dz));
      }
      if (k == k0A) {
#pragma unroll
        for (int q = 0; q < RPB; ++q)
          d2r[q] = (j > i0A + q) ? d2r[q] : kHugeD2;  // strict upper triangle
      }
      {
        const float mv = fminf(fminf(d2r[0], d2r[1]), fminf(d2r[2], d2r[3]));
        if (__ballot(mv < kThresh2) != 0ull) {
#pragma unroll
          for (int q = 0; q < RPB; ++q) {
            const float dist = __builtin_amdgcn_sqrtf(d2r[q] + kEps);
            accA[q] += fmaxf(kClashTol - dist, 0.f);
          }
        }
      }
      // --- tile B (active for k >= k0B; diagonal when k == k0B) ---
      if (k >= k0B) {
#pragma unroll
        for (int q = 0; q < RPB; ++q) {
          const float dx = c0x - pxB[q], dy = c0y - pyB[q], dz = c0z - pzB[q];
          d2r[q] = fmaf(dx, dx, fmaf(dy, dy, dz * dz));
        }
        if (k == k0B) {
#pragma unroll
          for (int q = 0; q < RPB; ++q)
            d2r[q] = (j > i0B + q) ? d2r[q] : kHugeD2;
        }
        const float mv = fminf(fminf(d2r[0], d2r[1]), fminf(d2r[2], d2r[3]));
        if (__ballot(mv < kThresh2) != 0ull) {
#pragma unroll
          for (int q = 0; q < RPB; ++q) {
            const float dist = __builtin_amdgcn_sqrtf(d2r[q] + kEps);
            accB[q] += fmaxf(kClashTol - dist, 0.f);
          }
        }
      }
      // rotate prefetch pipeline (apply sentinel to the new arrival)
      if (nmm == 0.f) { nx = kFarBase + 4.f * (float)jn; ny = 0.f; nz = 0.f; }
      c0x = c1x; c0y = c1y; c0z = c1z;
      c1x = nx;  c1y = ny;  c1z = nz;
    }
  }

  float cv = 0.f;
#pragma unroll
  for (int q = 0; q < RPB; ++q) cv += accA[q] + accB[q];

  // ---- tail (8 rows): near-diagonal cancel + bond + pm stencil ----
  float bv = 0.f, bm = 0.f, pm = 0.f;
  if (tid < 8) {
    const int i = (tid < 4) ? (i0A + tid) : (i0B + (tid - 4));
    const float mi = mb[i];
    const float xi = pb[3 * i], yi = pb[3 * i + 1], zi = pb[3 * i + 2];
    float sxi = xi, syi = yi, szi = zi;                 // sentineled copy
    if (mi == 0.f) { sxi = kFarBase + 4.f * (float)i; syi = 0.f; szi = 0.f; }
    const int jhi = (i + 2 > SEQ_L - 1) ? SEQ_L - 1 : i + 2;

    float nv = 0.f;                   // cancel exactly what the sweep added
    for (int jj = i + 1; jj <= jhi; ++jj) {
      float xj = pb[3 * jj], yj = pb[3 * jj + 1], zj = pb[3 * jj + 2];
      if (mb[jj] == 0.f) { xj = kFarBase + 4.f * (float)jj; yj = 0.f; zj = 0.f; }
      const float dx = xj - sxi, dy = yj - syi, dz = zj - szi;
      const float dist = __builtin_amdgcn_sqrtf(dx*dx + dy*dy + dz*dz + kEps);
      nv += fmaxf(kClashTol - dist, 0.f);
    }
    cv -= nv;

    float nm_ = 0.f;                  // real masks, |i-j|<=2 incl. j==i
    const int jlo = (i - 2 < 0) ? 0 : i - 2;
    for (int jj = jlo; jj <= jhi; ++jj) nm_ += mb[jj];
    pm = -mi * nm_;                   // msum^2 added by designated blocks

    if (i < SEQ_L - 1) {              // bond term: RAW positions, mask product
      const float dx = pb[3*(i+1)]   - xi;
      const float dy = pb[3*(i+1)+1] - yi;
      const float dz = pb[3*(i+1)+2] - zi;
      const float dist = __builtin_amdgcn_sqrtf(dx*dx + dy*dy + dz*dz + kEps);
      const float mj = mb[i + 1];
      bv = fmaxf(fabsf(dist - kIdeal) - kBondTol, 0.f) * mi * mj;
      bm = mi * mj;
    }
  }

  // ---- block reduction -> ONE plain float4 store (no atomics, no fences) ----
  bv = wred(bv); bm = wred(bm); cv = wred(cv); pm = wred(pm);
  if (lane == 0) {
    red4[wid][0] = bv; red4[wid][1] = bm;
    red4[wid][2] = cv; red4[wid][3] = pm;
  }
  __syncthreads();
  if (tid == 0) {
    float tbv = 0.f, tbm = 0.f, tcv = 0.f, tpm = 0.f;
#pragma unroll
    for (int w = 0; w < NWAVE; ++w) {
      tbv += red4[w][0]; tbm += red4[w][1];
      tcv += red4[w][2]; tpm += red4[w][3];
    }
    // x2: upper triangle -> full ordered sum; msq only in designated blocks
    partial[blockIdx.x] = make_float4(tbv, tbm, 2.f * tcv, tpm + msq);
  }
}

__global__ __launch_bounds__(TPB) void viol_reduce(
    const float4* __restrict__ partial, float* __restrict__ out) {
  __shared__ float red4[NWAVE][4];
  float bv = 0.f, bm = 0.f, cv = 0.f, pm = 0.f;
#pragma unroll
  for (int i = threadIdx.x; i < NBLOCKS; i += TPB) {
    float4 p = partial[i];
    bv += p.x; bm += p.y; cv += p.z; pm += p.w;
  }
  bv = wred(bv); bm = wred(bm); cv = wred(cv); pm = wred(pm);
  const int wid  = threadIdx.x >> 6;
  const int lane = threadIdx.x & 63;
  if (lane == 0) {
    red4[wid][0] = bv; red4[wid][1] = bm;
    red4[wid][2] = cv; red4[wid][3] = pm;
  }
  __syncthreads();
  if (threadIdx.x == 0) {
    float tbv = 0.f, tbm = 0.f, tcv = 0.f, tpm = 0.f;
#pragma unroll
    for (int w = 0; w < NWAVE; ++w) {
      tbv += red4[w][0]; tbm += red4[w][1];
      tcv += red4[w][2]; tpm += red4[w][3];
    }
    float bond  = tbv / (tbm + kEps);
    float clash = tcv / (tpm + kEps);
    out[0] = bond;
    out[1] = clash;
    out[2] = bond + clash;
  }
}

extern "C" void kernel_launch(void* const* d_in, const int* in_sizes, int n_in,
                              void* d_out, int out_size, void* d_ws, size_t ws_size,
                              hipStream_t stream) {
  const float* pos  = (const float*)d_in[0];
  const float* mask = (const float*)d_in[1];
  float* out = (float*)d_out;
  float4* partial = (float4*)d_ws;   // 2048 * 16 B = 32 KB scratch

  viol_main<<<dim3(NBLOCKS), dim3(TPB), 0, stream>>>(pos, mask, partial);
  viol_reduce<<<dim3(1), dim3(TPB), 0, stream>>>(partial, out);
}